// Round 1
// baseline (112.622 us; speedup 1.0000x reference)
//
#include <hip/hip_runtime.h>
#include <stdint.h>

using i32x4 = __attribute__((ext_vector_type(4))) int;

// ---------------- ws layout ----------------
// [0,    2048)  : double partials[256]
// [2048, 2056)  : double scale_d
// [2056, 2060)  : float  scale_f
// [4096, +128K) : float  fact[32768]
// [1MB,  +32MB) : int8   xq[32768*1024]
// [33MB, +1MB)  : int8   qw[1024*1024]

#define WS_SCALED   2048
#define WS_SCALEF   2056
#define WS_FACT     4096
#define WS_XQ       (1u << 20)
#define WS_QW       ((1u << 20) + (32u << 20))

// ---------------- kernel 1: partial sums of |w| (deterministic) ----------------
__global__ __launch_bounds__(256) void k_wabs_partial(const float* __restrict__ w,
                                                      double* __restrict__ partials) {
    int t = threadIdx.x;
    int b = blockIdx.x;
    const float4* w4 = (const float4*)(w + b * 4096);
    double s = 0.0;
#pragma unroll
    for (int i = 0; i < 4; ++i) {
        float4 v = w4[i * 256 + t];
        s += (double)fabsf(v.x) + (double)fabsf(v.y) +
             (double)fabsf(v.z) + (double)fabsf(v.w);
    }
#pragma unroll
    for (int off = 32; off > 0; off >>= 1) s += __shfl_down(s, off, 64);
    __shared__ double lds[4];
    if ((t & 63) == 0) lds[t >> 6] = s;
    __syncthreads();
    if (t == 0) partials[b] = ((lds[0] + lds[1]) + (lds[2] + lds[3]));
}

// ---------------- kernel 2: finalize scale ----------------
__global__ __launch_bounds__(256) void k_scale(const double* __restrict__ partials,
                                               double* __restrict__ scale_d,
                                               float* __restrict__ scale_f) {
    int t = threadIdx.x;
    double s = partials[t];
#pragma unroll
    for (int off = 32; off > 0; off >>= 1) s += __shfl_down(s, off, 64);
    __shared__ double lds[4];
    if ((t & 63) == 0) lds[t >> 6] = s;
    __syncthreads();
    if (t == 0) {
        double m = ((lds[0] + lds[1]) + (lds[2] + lds[3])) / 1048576.0;
        if (m < 1e-5) m = 1e-5;
        *scale_d = m;
        *scale_f = (float)m;
    }
}

// ---------------- kernel 3: ternary weight quant ----------------
// q = clip(rint(w/s),-1,1) == (|w| > 0.5*s) ? sign(w) : 0   (tie 0.5 -> 0, half-even)
__global__ __launch_bounds__(256) void k_wquant(const float* __restrict__ w,
                                                const double* __restrict__ scale_d,
                                                int8_t* __restrict__ qw) {
    double half_s = 0.5 * (*scale_d);
    int idx = blockIdx.x * 2048 + threadIdx.x * 8;
    float4 v0 = *(const float4*)(w + idx);
    float4 v1 = *(const float4*)(w + idx + 4);
    float f[8] = {v0.x, v0.y, v0.z, v0.w, v1.x, v1.y, v1.z, v1.w};
    union { char c[8]; int2 p; } u;
#pragma unroll
    for (int i = 0; i < 8; ++i) {
        char q = 0;
        if ((double)fabsf(f[i]) > half_s) q = (f[i] > 0.0f) ? 1 : -1;
        u.c[i] = q;
    }
    *(int2*)(qw + idx) = u.p;
}

// ---------------- kernel 4: per-token int8 activation quant (wave per token) ----------------
__device__ inline int q8pack(float4 f, float as) {
    int a = (int)fminf(fmaxf(rintf(f.x * as), -128.0f), 127.0f);
    int b = (int)fminf(fmaxf(rintf(f.y * as), -128.0f), 127.0f);
    int c = (int)fminf(fmaxf(rintf(f.z * as), -128.0f), 127.0f);
    int d = (int)fminf(fmaxf(rintf(f.w * as), -128.0f), 127.0f);
    return (a & 0xff) | ((b & 0xff) << 8) | ((c & 0xff) << 16) | ((d & 0xff) << 24);
}

__global__ __launch_bounds__(256) void k_aquant(const float* __restrict__ x,
                                                const float* __restrict__ scale_f,
                                                int8_t* __restrict__ xq,
                                                float* __restrict__ fact) {
    int wid = threadIdx.x >> 6;
    int lane = threadIdx.x & 63;
    int token = blockIdx.x * 4 + wid;
    const float* xr = x + (size_t)token * 1024;
    float4 v[4];
    float m = 0.0f;
#pragma unroll
    for (int c = 0; c < 4; ++c) {
        v[c] = *(const float4*)(xr + c * 256 + lane * 4);
        m = fmaxf(m, fmaxf(fmaxf(fabsf(v[c].x), fabsf(v[c].y)),
                           fmaxf(fabsf(v[c].z), fabsf(v[c].w))));
    }
#pragma unroll
    for (int off = 32; off > 0; off >>= 1) m = fmaxf(m, __shfl_xor(m, off, 64));
    m = fmaxf(m, 1e-5f);
    float as = 127.0f / m;
    int* xqo = (int*)xq;
#pragma unroll
    for (int c = 0; c < 4; ++c)
        xqo[token * 256 + c * 64 + lane] = q8pack(v[c], as);
    if (lane == 0) fact[token] = (*scale_f) / as;   // scale / act_scale
}

// ---------------- kernel 5: i8 MFMA GEMM ----------------
// A = xq [32768][1024] i8 row-major, Bt = qw [1024][1024] i8 row-major (N x K)
// out[t][o] = acc * fact[t] + bias[o]
// Tile 128x128, BK=64, 4 waves (2x2), each wave 64x64 via 4x4 of 16x16x64 MFMAs.
// LDS swizzle: col16 ^= ((row>>1)&3)<<4, applied on global source AND ds_read.

__device__ inline void gl_lds16(const void* g, void* l) {
    __builtin_amdgcn_global_load_lds((const __attribute__((address_space(1))) void*)g,
                                     (__attribute__((address_space(3))) void*)l, 16, 0, 0);
}

__global__ __launch_bounds__(256) void k_gemm(const int8_t* __restrict__ A,
                                              const int8_t* __restrict__ B,
                                              const float* __restrict__ fact,
                                              const float* __restrict__ bias,
                                              float* __restrict__ out) {
    __shared__ int8_t As[128 * 64];
    __shared__ int8_t Bs[128 * 64];
    int tid = threadIdx.x;
    int lane = tid & 63;
    int wm = (tid >> 6) >> 1;
    int wn = (tid >> 6) & 1;
    int tm = blockIdx.x >> 3;
    int tn = blockIdx.x & 7;

    const int8_t* Ab = A + (size_t)tm * 128 * 1024;
    const int8_t* Bb = B + (size_t)tn * 128 * 1024;

    i32x4 acc[4][4];
#pragma unroll
    for (int m = 0; m < 4; ++m)
#pragma unroll
        for (int n = 0; n < 4; ++n)
            acc[m][n] = (i32x4){0, 0, 0, 0};

    // precompute staging coords (2 chunks of A + 2 of B per thread per K-step)
    int c0 = tid;            // chunk ids
    int c1 = 256 + tid;
    int r0 = c0 >> 2, s0 = ((c0 & 3) << 4) ^ (((r0 >> 1) & 3) << 4);
    int r1 = c1 >> 2, s1 = ((c1 & 3) << 4) ^ (((r1 >> 1) & 3) << 4);

    for (int kt = 0; kt < 1024; kt += 64) {
        gl_lds16(Ab + (size_t)r0 * 1024 + kt + s0, As + c0 * 16);
        gl_lds16(Ab + (size_t)r1 * 1024 + kt + s1, As + c1 * 16);
        gl_lds16(Bb + (size_t)r0 * 1024 + kt + s0, Bs + c0 * 16);
        gl_lds16(Bb + (size_t)r1 * 1024 + kt + s1, Bs + c1 * 16);
        __syncthreads();

        i32x4 af[4], bf[4];
        int k0 = (lane >> 4) << 4;
#pragma unroll
        for (int m = 0; m < 4; ++m) {
            int r = wm * 64 + m * 16 + (lane & 15);
            af[m] = *(const i32x4*)(As + r * 64 + (k0 ^ (((r >> 1) & 3) << 4)));
        }
#pragma unroll
        for (int n = 0; n < 4; ++n) {
            int r = wn * 64 + n * 16 + (lane & 15);
            bf[n] = *(const i32x4*)(Bs + r * 64 + (k0 ^ (((r >> 1) & 3) << 4)));
        }
#pragma unroll
        for (int m = 0; m < 4; ++m)
#pragma unroll
            for (int n = 0; n < 4; ++n)
                acc[m][n] = __builtin_amdgcn_mfma_i32_16x16x64_i8(af[m], bf[n], acc[m][n], 0, 0, 0);
        __syncthreads();
    }

    // epilogue: out[token][col] = acc * fact[token] + bias[col]
    int col0 = tn * 128 + wn * 64 + (lane & 15);
    int row0 = tm * 128 + wm * 64 + ((lane >> 4) << 2);
    float bv[4];
#pragma unroll
    for (int n = 0; n < 4; ++n) bv[n] = bias[col0 + n * 16];
#pragma unroll
    for (int m = 0; m < 4; ++m) {
        int rbase = row0 + m * 16;
        float fr[4];
#pragma unroll
        for (int r = 0; r < 4; ++r) fr[r] = fact[rbase + r];
#pragma unroll
        for (int n = 0; n < 4; ++n) {
#pragma unroll
            for (int r = 0; r < 4; ++r) {
                out[(size_t)(rbase + r) * 1024 + col0 + n * 16] =
                    (float)acc[m][n][r] * fr[r] + bv[n];
            }
        }
    }
}

extern "C" void kernel_launch(void* const* d_in, const int* in_sizes, int n_in,
                              void* d_out, int out_size, void* d_ws, size_t ws_size,
                              hipStream_t stream) {
    const float* x    = (const float*)d_in[0];
    const float* w    = (const float*)d_in[1];
    const float* bias = (const float*)d_in[2];
    float* out = (float*)d_out;
    char* ws = (char*)d_ws;

    double* partials = (double*)ws;
    double* scale_d  = (double*)(ws + WS_SCALED);
    float*  scale_f  = (float*)(ws + WS_SCALEF);
    float*  fact     = (float*)(ws + WS_FACT);
    int8_t* xq       = (int8_t*)(ws + WS_XQ);
    int8_t* qw       = (int8_t*)(ws + WS_QW);

    k_wabs_partial<<<256, 256, 0, stream>>>(w, partials);
    k_scale<<<1, 256, 0, stream>>>(partials, scale_d, scale_f);
    k_wquant<<<512, 256, 0, stream>>>(w, scale_d, qw);
    k_aquant<<<8192, 256, 0, stream>>>(x, scale_f, xq, fact);
    k_gemm<<<2048, 256, 0, stream>>>(xq, qw, fact, bias, out);
}

// Round 2
// 97.746 us; speedup vs baseline: 1.1522x; 1.1522x over previous
//
#include <hip/hip_runtime.h>
#include <stdint.h>

using i32x4 = __attribute__((ext_vector_type(4))) int;

// ---------------- ws layout ----------------
#define WS_SCALED   2048
#define WS_SCALEF   2056
#define WS_FACT     4096
#define WS_XQ       (1u << 20)
#define WS_QW       ((1u << 20) + (32u << 20))

// ---------------- kernel 1: partial sums of |w| (deterministic) ----------------
__global__ __launch_bounds__(256) void k_wabs_partial(const float* __restrict__ w,
                                                      double* __restrict__ partials) {
    int t = threadIdx.x;
    int b = blockIdx.x;
    const float4* w4 = (const float4*)(w + b * 4096);
    double s = 0.0;
#pragma unroll
    for (int i = 0; i < 4; ++i) {
        float4 v = w4[i * 256 + t];
        s += (double)fabsf(v.x) + (double)fabsf(v.y) +
             (double)fabsf(v.z) + (double)fabsf(v.w);
    }
#pragma unroll
    for (int off = 32; off > 0; off >>= 1) s += __shfl_down(s, off, 64);
    __shared__ double lds[4];
    if ((t & 63) == 0) lds[t >> 6] = s;
    __syncthreads();
    if (t == 0) partials[b] = ((lds[0] + lds[1]) + (lds[2] + lds[3]));
}

// ---------------- kernel 2: finalize scale ----------------
__global__ __launch_bounds__(256) void k_scale(const double* __restrict__ partials,
                                               double* __restrict__ scale_d,
                                               float* __restrict__ scale_f) {
    int t = threadIdx.x;
    double s = partials[t];
#pragma unroll
    for (int off = 32; off > 0; off >>= 1) s += __shfl_down(s, off, 64);
    __shared__ double lds[4];
    if ((t & 63) == 0) lds[t >> 6] = s;
    __syncthreads();
    if (t == 0) {
        double m = ((lds[0] + lds[1]) + (lds[2] + lds[3])) / 1048576.0;
        if (m < 1e-5) m = 1e-5;
        *scale_d = m;
        *scale_f = (float)m;
    }
}

// ---------------- kernel 3: ternary weight quant ----------------
__global__ __launch_bounds__(256) void k_wquant(const float* __restrict__ w,
                                                const double* __restrict__ scale_d,
                                                int8_t* __restrict__ qw) {
    double half_s = 0.5 * (*scale_d);
    int idx = blockIdx.x * 2048 + threadIdx.x * 8;
    float4 v0 = *(const float4*)(w + idx);
    float4 v1 = *(const float4*)(w + idx + 4);
    float f[8] = {v0.x, v0.y, v0.z, v0.w, v1.x, v1.y, v1.z, v1.w};
    union { char c[8]; int2 p; } u;
#pragma unroll
    for (int i = 0; i < 8; ++i) {
        char q = 0;
        if ((double)fabsf(f[i]) > half_s) q = (f[i] > 0.0f) ? 1 : -1;
        u.c[i] = q;
    }
    *(int2*)(qw + idx) = u.p;
}

// ---------------- kernel 4: per-token int8 activation quant ----------------
__device__ inline int q8pack(float4 f, float as) {
    int a = (int)fminf(fmaxf(rintf(f.x * as), -128.0f), 127.0f);
    int b = (int)fminf(fmaxf(rintf(f.y * as), -128.0f), 127.0f);
    int c = (int)fminf(fmaxf(rintf(f.z * as), -128.0f), 127.0f);
    int d = (int)fminf(fmaxf(rintf(f.w * as), -128.0f), 127.0f);
    return (a & 0xff) | ((b & 0xff) << 8) | ((c & 0xff) << 16) | ((d & 0xff) << 24);
}

__global__ __launch_bounds__(256) void k_aquant(const float* __restrict__ x,
                                                const float* __restrict__ scale_f,
                                                int8_t* __restrict__ xq,
                                                float* __restrict__ fact) {
    int wid = threadIdx.x >> 6;
    int lane = threadIdx.x & 63;
    int token = blockIdx.x * 4 + wid;
    const float* xr = x + (size_t)token * 1024;
    float4 v[4];
    float m = 0.0f;
#pragma unroll
    for (int c = 0; c < 4; ++c) {
        v[c] = *(const float4*)(xr + c * 256 + lane * 4);
        m = fmaxf(m, fmaxf(fmaxf(fabsf(v[c].x), fabsf(v[c].y)),
                           fmaxf(fabsf(v[c].z), fabsf(v[c].w))));
    }
#pragma unroll
    for (int off = 32; off > 0; off >>= 1) m = fmaxf(m, __shfl_xor(m, off, 64));
    m = fmaxf(m, 1e-5f);
    float as = 127.0f / m;
    int* xqo = (int*)xq;
#pragma unroll
    for (int c = 0; c < 4; ++c)
        xqo[token * 256 + c * 64 + lane] = q8pack(v[c], as);
    if (lane == 0) fact[token] = (*scale_f) / as;
}

// ---------------- kernel 5: i8 MFMA GEMM, 256x256 tile, 8-phase schedule ----------------
// A = xq [32768][1024] i8, B = qw [1024][1024] i8 (both row-major over K)
// BM=BN=256, BK=128 i8 (=128 B rows, same byte geometry as the bf16 template).
// 8 waves (2M x 4N), per-wave output 128x64. LDS 128 KiB (2 dbuf x (A+B) 32 KiB).
// Phases per K-tile (zigzag quadrants): Q00, Q01, Q11, Q10.
//   per phase: ds_read subtile | 1 staging unit (2 x global_load_lds) |
//              barrier | lgkmcnt(0) | setprio(1) | 16 MFMA | setprio(0) | barrier
// vmcnt(6) once per K-tile at phase 3 (3 x 2-load units in flight).
// Swizzle: slot ^= (row & 7), applied on pre-swizzled global source AND ds_read.

__device__ __forceinline__ void gl_lds16(const void* g, void* l) {
    __builtin_amdgcn_global_load_lds((const __attribute__((address_space(1))) void*)g,
                                     (__attribute__((address_space(3))) void*)l, 16, 0, 0);
}

#define PH(MQ, NQ) \
    __builtin_amdgcn_s_barrier(); \
    asm volatile("s_waitcnt lgkmcnt(0)" ::: "memory"); \
    __builtin_amdgcn_sched_barrier(0); \
    __builtin_amdgcn_s_setprio(1); \
    _Pragma("unroll") \
    for (int m = 0; m < 4; ++m) \
    _Pragma("unroll") \
    for (int n = 0; n < 2; ++n) \
    _Pragma("unroll") \
    for (int kk = 0; kk < 2; ++kk) \
        acc[MQ*4+m][NQ*2+n] = __builtin_amdgcn_mfma_i32_16x16x64_i8( \
            aR[m][kk], bR[n][kk], acc[MQ*4+m][NQ*2+n], 0, 0, 0); \
    __builtin_amdgcn_s_setprio(0); \
    __builtin_amdgcn_s_barrier();

__global__ __launch_bounds__(512, 2) void k_gemm2(const int8_t* __restrict__ A,
                                                  const int8_t* __restrict__ B,
                                                  const float* __restrict__ fact,
                                                  const float* __restrict__ bias,
                                                  float* __restrict__ out) {
    __shared__ int8_t As[2][256 * 128];
    __shared__ int8_t Bs[2][256 * 128];
    const int tid  = threadIdx.x;
    const int lane = tid & 63;
    const int wid  = tid >> 6;
    const int wm   = wid >> 2;     // 0..1
    const int wn   = wid & 3;      // 0..3
    const int l15  = lane & 15;
    const int l4   = lane >> 4;

    // XCD-aware swizzle (512 blocks % 8 == 0 -> simple bijective form)
    int bid = blockIdx.x;
    int swz = (bid & 7) * 64 + (bid >> 3);
    int tm = swz >> 2;             // 0..127
    int tn = swz & 3;              // 0..3

    const int8_t* Ag = A + (size_t)tm * 256 * 1024;
    const int8_t* Bg = B + (size_t)tn * 256 * 1024;

    const int sr  = tid >> 3;      // 0..63
    const int ssl = tid & 7;       // slot 0..7

    // stage 64 contiguous LDS rows of A starting at r0 (A phys row == tile row)
    auto stageA = [&](int bi, int r0, int kb) {
        int pr = r0 + sr;
        gl_lds16(Ag + (size_t)pr * 1024 + kb + ((ssl ^ (pr & 7)) << 4),
                 &As[bi][r0 * 128 + tid * 16]);
    };
    // B phys row pr -> tile row br (stripes of 32 packed so read-phase regions are contiguous)
    auto stageB = [&](int bi, int r0, int kb) {
        int pr = r0 + sr;
        int br = ((pr & 127) >> 5) * 64 + ((pr >> 7) << 5) + (pr & 31);
        gl_lds16(Bg + (size_t)br * 1024 + kb + ((ssl ^ (pr & 7)) << 4),
                 &Bs[bi][r0 * 128 + tid * 16]);
    };
    auto ldA = [&](int bi, int mq, int m, int kk) -> i32x4 {
        int r  = wm * 128 + mq * 64 + m * 16 + l15;
        int sl = ((kk << 2) + l4) ^ (r & 7);
        return *(const i32x4*)&As[bi][r * 128 + (sl << 4)];
    };
    auto ldB = [&](int bi, int nq, int n, int kk) -> i32x4 {
        int pr = nq * 128 + wn * 32 + n * 16 + l15;
        int sl = ((kk << 2) + l4) ^ (pr & 7);
        return *(const i32x4*)&Bs[bi][pr * 128 + (sl << 4)];
    };

    i32x4 acc[8][4];
#pragma unroll
    for (int i = 0; i < 8; ++i)
#pragma unroll
        for (int j = 0; j < 4; ++j) acc[i][j] = (i32x4){0, 0, 0, 0};

    // prologue: tile0 fully (8 units of 64 rows), tile1 all except uBe(1)
    stageA(0, 0, 0);     stageA(0, 128, 0);     // uAe(0)  read ph0
    stageA(0, 64, 0);    stageA(0, 192, 0);     // uAo(0)  read ph2
    stageB(0, 0, 0);     stageB(0, 64, 0);      // uBe(0)  read ph0, ph3
    stageB(0, 128, 0);   stageB(0, 192, 0);     // uBo(0)  read ph1
    stageA(1, 0, 128);   stageA(1, 128, 128);   // uAe(1)
    stageA(1, 64, 128);  stageA(1, 192, 128);   // uAo(1)
    stageB(1, 128, 128); stageB(1, 192, 128);   // uBo(1)
    asm volatile("s_waitcnt vmcnt(6)" ::: "memory");   // tile0 landed
    __builtin_amdgcn_s_barrier();

    i32x4 aR[4][2], bR[2][2];

    for (int t = 0; t < 8; ++t) {
        const int bi  = t & 1;
        const int kb1 = (t + 1) << 7;
        const int kb2 = (t + 2) << 7;

        // ---- phase 0 : Q(0,0) — read A-even + B-even; stage uBe(t+1)
#pragma unroll
        for (int m = 0; m < 4; ++m) { aR[m][0] = ldA(bi, 0, m, 0); aR[m][1] = ldA(bi, 0, m, 1); }
#pragma unroll
        for (int n = 0; n < 2; ++n) { bR[n][0] = ldB(bi, 0, n, 0); bR[n][1] = ldB(bi, 0, n, 1); }
        if (t <= 6) { stageB(bi ^ 1, 0, kb1); stageB(bi ^ 1, 64, kb1); }
        PH(0, 0)

        // ---- phase 1 : Q(0,1) — read B-odd; stage uAe(t+2)
#pragma unroll
        for (int n = 0; n < 2; ++n) { bR[n][0] = ldB(bi, 1, n, 0); bR[n][1] = ldB(bi, 1, n, 1); }
        if (t <= 5) { stageA(bi, 0, kb2); stageA(bi, 128, kb2); }
        PH(0, 1)

        // ---- phase 2 : Q(1,1) — read A-odd (reuse B-odd regs)
#pragma unroll
        for (int m = 0; m < 4; ++m) { aR[m][0] = ldA(bi, 1, m, 0); aR[m][1] = ldA(bi, 1, m, 1); }
        PH(1, 1)

        // ---- phase 3 : Q(1,0) — re-read B-even; stage uAo(t+2), uBo(t+2); counted vmcnt
#pragma unroll
        for (int n = 0; n < 2; ++n) { bR[n][0] = ldB(bi, 0, n, 0); bR[n][1] = ldB(bi, 0, n, 1); }
        if (t <= 5) { stageA(bi, 64, kb2); stageA(bi, 192, kb2);
                      stageB(bi, 128, kb2); stageB(bi, 192, kb2); }
        if (t < 6) asm volatile("s_waitcnt vmcnt(6)" ::: "memory");
        else       asm volatile("s_waitcnt vmcnt(0)" ::: "memory");
        PH(1, 0)
    }

    // ---- epilogue ----
    const int col00 = tn * 256 + wn * 64 + l15;
    const int row00 = tm * 256 + wm * 128 + (l4 << 2);
    float bv[2][2];
#pragma unroll
    for (int nq = 0; nq < 2; ++nq)
#pragma unroll
        for (int n = 0; n < 2; ++n) bv[nq][n] = bias[col00 + nq * 32 + n * 16];
#pragma unroll
    for (int mq = 0; mq < 2; ++mq)
#pragma unroll
    for (int m = 0; m < 4; ++m) {
        int rbase = row00 + mq * 64 + m * 16;
        float fr[4];
#pragma unroll
        for (int r = 0; r < 4; ++r) fr[r] = fact[rbase + r];
#pragma unroll
        for (int nq = 0; nq < 2; ++nq)
#pragma unroll
        for (int n = 0; n < 2; ++n) {
            int c = col00 + nq * 32 + n * 16;
#pragma unroll
            for (int r = 0; r < 4; ++r)
                out[(size_t)(rbase + r) * 1024 + c] =
                    (float)acc[mq * 4 + m][nq * 2 + n][r] * fr[r] + bv[nq][n];
        }
    }
}

extern "C" void kernel_launch(void* const* d_in, const int* in_sizes, int n_in,
                              void* d_out, int out_size, void* d_ws, size_t ws_size,
                              hipStream_t stream) {
    const float* x    = (const float*)d_in[0];
    const float* w    = (const float*)d_in[1];
    const float* bias = (const float*)d_in[2];
    float* out = (float*)d_out;
    char* ws = (char*)d_ws;

    double* partials = (double*)ws;
    double* scale_d  = (double*)(ws + WS_SCALED);
    float*  scale_f  = (float*)(ws + WS_SCALEF);
    float*  fact     = (float*)(ws + WS_FACT);
    int8_t* xq       = (int8_t*)(ws + WS_XQ);
    int8_t* qw       = (int8_t*)(ws + WS_QW);

    k_wabs_partial<<<256, 256, 0, stream>>>(w, partials);
    k_scale<<<1, 256, 0, stream>>>(partials, scale_d, scale_f);
    k_wquant<<<512, 256, 0, stream>>>(w, scale_d, qw);
    k_aquant<<<8192, 256, 0, stream>>>(x, scale_f, xq, fact);
    k_gemm2<<<512, 512, 0, stream>>>(xq, qw, fact, bias, out);
}